// Round 4
// baseline (280.808 us; speedup 1.0000x reference)
//
#include <hip/hip_runtime.h>

#define NPTS 65536
#define BATCH 2
#define CCH 128
#define HIDC 64
#define LDB 520      // k_zr bext row stride u16 (512+8 pad)
#define LDB2 264     // k_q bext row stride u16 (256+8 pad)
#define PLD 130      // k_pack tile row stride u16

typedef unsigned short u16;
typedef unsigned int u32;
typedef __bf16 bf16_t;
typedef bf16_t bf16x8 __attribute__((ext_vector_type(8)));
typedef float f32x4 __attribute__((ext_vector_type(4)));
typedef float f32x2 __attribute__((ext_vector_type(2)));

__device__ __forceinline__ u16 f2bf(float f){
  union { float f; unsigned u; } v; v.f = f;
  unsigned r = v.u + 0x7FFFu + ((v.u >> 16) & 1u);
  return (u16)(r >> 16);
}
__device__ __forceinline__ float bf2f(u16 u){
  union { unsigned u; float f; } v; v.u = ((unsigned)u) << 16; return v.f;
}
__device__ __forceinline__ u32 pkrn(float a, float b){
  union { float f; u32 u; } ua, ub; ua.f = a; ub.f = b;
  return ((ua.u + 0x8000u) >> 16) | ((ub.u + 0x8000u) & 0xffff0000u);
}
__device__ __forceinline__ float sigmoidf_(float v){ return 1.f/(1.f+__expf(-v)); }
__device__ __forceinline__ float tanhf_(float v){
  v = fminf(10.f, fmaxf(-10.f, v));
  float e = __expf(2.f*v);
  return (e-1.f)/(e+1.f);
}

// Barrier with LDS-visibility only: does NOT drain vmcnt, so global loads
// issued before it stay in flight across the barrier (unlike __syncthreads).
__device__ __forceinline__ void bar_lgkm(){
  asm volatile("s_waitcnt lgkmcnt(0)" ::: "memory");
  __builtin_amdgcn_s_barrier();
  __builtin_amdgcn_sched_barrier(0);
}

// A matrices (bf16), fragment-permuted. First 98304: Az|Ar|Aq at K=512.
// Then 16384: Aqrh at K=256 (c in [0,64)).
__global__ __launch_bounds__(256) void kprep(
    const float* __restrict__ wz, const float* __restrict__ wzp, const float* __restrict__ bzp,
    const float* __restrict__ wr, const float* __restrict__ wrp, const float* __restrict__ brp,
    const float* __restrict__ wq, const float* __restrict__ wqp, const float* __restrict__ bqp,
    u16* __restrict__ A){
  int idx = blockIdx.x*256 + threadIdx.x;          // 0..114687
  if (idx < 98304){
    int t = idx & 7, o = (idx>>3)&63, quad = (idx>>9)&3, s = (idx>>11)&15, g = idx>>15;
    int pk = s*32 + quad*8 + t;
    int j = pk>>7, chunk = (pk>>3)&15, tt = pk&7;
    int orig = chunk*32 + j*8 + tt;
    int c = orig>>2, m = orig&3;
    const float* W  = (g==0)? wz  : (g==1)? wr  : wq;
    const float* wp = (g==0)? wzp : (g==1)? wrp : wqp;
    const float* bp = (g==0)? bzp : (g==1)? brp : bqp;
    float coef = m ? wp[c*3 + m - 1] : bp[c];
    A[idx] = f2bf(W[o*CCH + c] * coef);
  } else {
    int i2 = idx - 98304;
    int t = i2 & 7, o = (i2>>3)&63, quad = (i2>>9)&3, s = (i2>>11)&7;
    int k2 = s*32 + quad*8 + t;
    int j = k2>>6, chunk = (k2>>3)&7, tt = k2&7;
    int orig = chunk*32 + j*8 + tt;
    int c = orig>>2, m = orig&3;                   // c in [0,64): rh channels
    float coef = m ? wqp[c*3 + m - 1] : bqp[c];
    A[idx] = f2bf(wq[o*CCH + c] * coef);
  }
}

// Transpose h,x [B,64,N] fp32 -> hxT [B,N,128] bf16 rows.
__global__ __launch_bounds__(256) void k_pack(const float* __restrict__ h,
    const float* __restrict__ x, u16* __restrict__ hxT){
  __shared__ __align__(16) u16 tile[64*PLD];
  int tid = threadIdx.x;
  int b = blockIdx.x >> 10, n0 = (blockIdx.x & 1023) << 6;
  #pragma unroll
  for (int i = 0; i < 8; ++i){
    int cc = (tid>>4) + i*16;                      // 0..127
    int nn = (tid & 15)*4;
    const float* src = (cc < HIDC)
        ? (h + (((size_t)(b*HIDC + cc))<<16) + n0 + nn)
        : (x + (((size_t)(b*HIDC + cc - HIDC))<<16) + n0 + nn);
    float4 v = *(const float4*)src;
    tile[(nn+0)*PLD + cc] = f2bf(v.x);
    tile[(nn+1)*PLD + cc] = f2bf(v.y);
    tile[(nn+2)*PLD + cc] = f2bf(v.z);
    tile[(nn+3)*PLD + cc] = f2bf(v.w);
  }
  __syncthreads();
  #pragma unroll
  for (int i = 0; i < 4; ++i){
    int tsk = tid + (i<<8);                        // 0..1023: 64 n x 16 chunks
    int n = tsk>>4, ch = (tsk&15)*8;
    uint4 v = *(const uint4*)(tile + n*PLD + ch);
    *(uint4*)(hxT + (((size_t)(b<<16) + n0 + n)<<7) + ch) = v;
  }
}

// Moment accumulation on f32x2 (v_pk_fma_f32).
#define ACCUM(gv, rv) { \
  u32 dw_[4] = {gv.x, gv.y, gv.z, gv.w}; \
  _Pragma("unroll") \
  for (int q_ = 0; q_ < 4; ++q_){ \
    union { u32 u; float f; } lo_, hi_; \
    lo_.u = dw_[q_] << 16; hi_.u = dw_[q_] & 0xffff0000u; \
    f32x2 v_ = {lo_.f, hi_.f}; \
    m0[q_] += v_; mx[q_] += rv.x * v_; my[q_] += rv.y * v_; mz[q_] += rv.z * v_; \
  } }

#define PACKROW(row, CHOFF, STRIDE) { \
  _Pragma("unroll") \
  for (int j_ = 0; j_ < 4; ++j_){ \
    uint4 v_; \
    v_.x = pkrn(m0[j_].x, mx[j_].x); v_.y = pkrn(my[j_].x, mz[j_].x); \
    v_.z = pkrn(m0[j_].y, mx[j_].y); v_.w = pkrn(my[j_].y, mz[j_].y); \
    *(uint4*)((row) + j_*(STRIDE) + (CHOFF)) = v_; \
  } }

#define MFMA_BF16(A_, B_, C_) __builtin_amdgcn_mfma_f32_16x16x32_bf16(A_, B_, C_, 0, 0, 0)

// ---------------- k_zr: z & r gates + q x-partial -----------------
// 64 points/block as TWO pipelined 32-pt tiles sharing one bext buffer.
// Tile-1 gathers issued under tile-0 MFMA; barriers never drain vmcnt.
__global__ __launch_bounds__(256, 4) void k_zr(
    const float* __restrict__ xyz, const float* __restrict__ h,
    const int* __restrict__ knn,
    const float* __restrict__ bz_out, const float* __restrict__ br_out,
    const u16* __restrict__ Azr,    // Az at 0, Ar at +32768, Aq at +65536
    const u16* __restrict__ hxT, u16* __restrict__ rhT,
    u32* __restrict__ zq_ws)
{
  __shared__ __align__(16) u16 bext[32*LDB];       // 33280 B
  __shared__ __align__(16) float4 relk[2][128];    // 4096 B
  __shared__ __align__(16) int4 jlds[2][32];       // 1024 B -> 38400 B total

  int tid = threadIdx.x; int lane = tid & 63; int wv = tid >> 6;
  int l15 = lane & 15, quad = lane >> 4;
  int b = blockIdx.x >> 10, nb = (blockIdx.x & 1023) << 6;
  size_t bN = (size_t)b * NPTS;

  // P0: knn + xyz + relk for BOTH tiles; issue tile-0 h prefetch.
  {
    int t_ = tid >> 7, p_ = (tid >> 2) & 31, k_ = tid & 3;
    int n_ = nb + t_*32 + p_;
    int j = knn[((bN + n_) << 2) + k_];
    ((int*)jlds)[tid] = j;
    const float* xb = xyz + (size_t)b*3*NPTS;
    float cx = xb[n_], cy = xb[NPTS + n_], cz = xb[2*NPTS + n_];
    relk[t_][p_*4 + k_] = make_float4(xb[j]-cx, xb[NPTS+j]-cy, xb[2*NPTS+j]-cz, 0.f);
  }
  float hp0[8];
  #pragma unroll
  for (int nt = 0; nt < 2; ++nt)
    #pragma unroll
    for (int reg = 0; reg < 4; ++reg)
      hp0[nt*4+reg] = h[(((size_t)(b*HIDC + wv*16 + quad*4 + reg))<<16) + nb + nt*16 + l15];
  bar_lgkm();

  const u16* hxTb = hxT + (bN << 7);
  int pA = tid >> 4, chk = tid & 15;
  const u16* cbp = hxTb + chk*8;

#define GATH_ZR(G, JL) { \
  int4 jA_ = (JL)[pA], jB_ = (JL)[pA+16]; \
  G[0] = *(const uint4*)(cbp + (((size_t)jA_.x)<<7)); \
  G[1] = *(const uint4*)(cbp + (((size_t)jA_.y)<<7)); \
  G[2] = *(const uint4*)(cbp + (((size_t)jA_.z)<<7)); \
  G[3] = *(const uint4*)(cbp + (((size_t)jA_.w)<<7)); \
  G[4] = *(const uint4*)(cbp + (((size_t)jB_.x)<<7)); \
  G[5] = *(const uint4*)(cbp + (((size_t)jB_.y)<<7)); \
  G[6] = *(const uint4*)(cbp + (((size_t)jB_.z)<<7)); \
  G[7] = *(const uint4*)(cbp + (((size_t)jB_.w)<<7)); }

#define MOMPACK_ZR(G, RK) { \
  { float4 r0 = (RK)[pA*4+0], r1 = (RK)[pA*4+1], r2 = (RK)[pA*4+2], r3 = (RK)[pA*4+3]; \
    f32x2 m0[4] = {{0,0},{0,0},{0,0},{0,0}}, mx[4] = {{0,0},{0,0},{0,0},{0,0}}; \
    f32x2 my[4] = {{0,0},{0,0},{0,0},{0,0}}, mz[4] = {{0,0},{0,0},{0,0},{0,0}}; \
    ACCUM(G[0], r0); ACCUM(G[1], r1); ACCUM(G[2], r2); ACCUM(G[3], r3); \
    PACKROW(bext + pA*LDB, chk*8, 128); } \
  { float4 r0 = (RK)[(pA+16)*4+0], r1 = (RK)[(pA+16)*4+1], r2 = (RK)[(pA+16)*4+2], r3 = (RK)[(pA+16)*4+3]; \
    f32x2 m0[4] = {{0,0},{0,0},{0,0},{0,0}}, mx[4] = {{0,0},{0,0},{0,0},{0,0}}; \
    f32x2 my[4] = {{0,0},{0,0},{0,0},{0,0}}, mz[4] = {{0,0},{0,0},{0,0},{0,0}}; \
    ACCUM(G[4], r0); ACCUM(G[5], r1); ACCUM(G[6], r2); ACCUM(G[7], r3); \
    PACKROW(bext + (pA+16)*LDB, chk*8, 128); } }

  int orow = wv*16 + l15;
  const u16* Abase = Azr + ((size_t)(quad*64 + orow))*8;   // + s*2048 walks s-slices
  f32x4 accz[2], accr[2], accq[2];
  bf16x8 az0[4], ar0[4], aq0[2], az1[4], ar1[4], aq1[2];

#define LOADA(AZ, AR, AQ, SS) { \
  _Pragma("unroll") \
  for (int j = 0; j < 4; ++j){ \
    AZ[j] = *(const bf16x8*)(Abase + ((SS)*4 + j)*2048); \
    AR[j] = *(const bf16x8*)(Abase + 32768 + ((SS)*4 + j)*2048); \
  } \
  AQ[0] = *(const bf16x8*)(Abase + 65536 + ((SS)*4 + 2)*2048); \
  AQ[1] = *(const bf16x8*)(Abase + 65536 + ((SS)*4 + 3)*2048); }

#define MFMAG(AZ, AR, AQ, SS) { \
  _Pragma("unroll") \
  for (int j = 0; j < 4; ++j){ \
    int s_ = (SS)*4 + j; \
    _Pragma("unroll") \
    for (int nt = 0; nt < 2; ++nt){ \
      bf16x8 bb = *(const bf16x8*)(bext + (nt*16 + l15)*LDB + s_*32 + quad*8); \
      accz[nt] = MFMA_BF16(AZ[j], bb, accz[nt]); \
      accr[nt] = MFMA_BF16(AR[j], bb, accr[nt]); \
      if (j >= 2) accq[nt] = MFMA_BF16(AQ[j-2], bb, accq[nt]); \
    } } }

// Epilogue: compute+stage (bext reuse), barrier, vectorized stores.
#define EPI_ZR(HP, N0) { \
  u32* zqst = (u32*)bext;            /* [64 o][40] u32 = 10240 B */ \
  u16* rhst = bext + 5120;           /* [32 p][72] u16 = 4608 B */ \
  _Pragma("unroll") \
  for (int nt = 0; nt < 2; ++nt){ \
    _Pragma("unroll") \
    for (int reg = 0; reg < 4; ++reg){ \
      int o = wv*16 + quad*4 + reg; \
      int p = nt*16 + l15; \
      float zf = sigmoidf_(accz[nt][reg] + bz_out[o]); \
      float rf = sigmoidf_(accr[nt][reg] + br_out[o]); \
      zqst[o*40 + p] = (u32)f2bf(zf) | (((u32)f2bf(accq[nt][reg])) << 16); \
      rhst[p*72 + o] = f2bf(rf * HP[nt*4+reg]); \
    } } \
  bar_lgkm(); \
  _Pragma("unroll") \
  for (int i_ = 0; i_ < 2; ++i_){ \
    int task = tid + (i_<<8); \
    int o = task >> 3, c4 = (task & 7)*4; \
    uint4 v = *(const uint4*)(zqst + o*40 + c4); \
    *(uint4*)(zq_ws + (((size_t)(b*HIDC + o))<<16) + (N0) + c4) = v; \
  } \
  { int p = tid >> 3, ch = (tid & 7)*8; \
    uint4 v = *(const uint4*)(rhst + p*72 + ch); \
    *(uint4*)(rhT + ((bN + (N0) + p)<<6) + ch) = v; } }

  uint4 g0[8], g1[8];
  // ---- tile 0 ----
  GATH_ZR(g0, jlds[0]);
  __builtin_amdgcn_sched_barrier(0);
  MOMPACK_ZR(g0, relk[0]);
  bar_lgkm();

  #pragma unroll
  for (int nt = 0; nt < 2; ++nt){
    accz[nt] = (f32x4){0,0,0,0}; accr[nt] = (f32x4){0,0,0,0}; accq[nt] = (f32x4){0,0,0,0};
  }
  LOADA(az0, ar0, aq0, 0);
  LOADA(az1, ar1, aq1, 1);
  MFMAG(az0, ar0, aq0, 0);
  LOADA(az0, ar0, aq0, 2);
  MFMAG(az1, ar1, aq1, 1);
  LOADA(az1, ar1, aq1, 3);
  // all tile-0 A loads issued; now issue tile-1 gathers (they ride under
  // the remaining MFMAs + epilogue; no later vm-wait precedes them)
  GATH_ZR(g1, jlds[1]);
  __builtin_amdgcn_sched_barrier(0);
  MFMAG(az0, ar0, aq0, 2);
  MFMAG(az1, ar1, aq1, 3);
  bar_lgkm();          // bext MFMA reads done -> staging may overwrite

  EPI_ZR(hp0, nb);
  float hp1[8];
  #pragma unroll
  for (int nt = 0; nt < 2; ++nt)
    #pragma unroll
    for (int reg = 0; reg < 4; ++reg)
      hp1[nt*4+reg] = h[(((size_t)(b*HIDC + wv*16 + quad*4 + reg))<<16) + nb + 32 + nt*16 + l15];
  bar_lgkm();          // staging LDS reads done -> bext reusable

  // ---- tile 1 ----
  MOMPACK_ZR(g1, relk[1]);
  bar_lgkm();
  #pragma unroll
  for (int nt = 0; nt < 2; ++nt){
    accz[nt] = (f32x4){0,0,0,0}; accr[nt] = (f32x4){0,0,0,0}; accq[nt] = (f32x4){0,0,0,0};
  }
  LOADA(az0, ar0, aq0, 0);
  LOADA(az1, ar1, aq1, 1);
  MFMAG(az0, ar0, aq0, 0);
  LOADA(az0, ar0, aq0, 2);
  MFMAG(az1, ar1, aq1, 1);
  LOADA(az1, ar1, aq1, 3);
  MFMAG(az0, ar0, aq0, 2);
  MFMAG(az1, ar1, aq1, 3);
  bar_lgkm();
  EPI_ZR(hp1, nb + 32);
}

// ---------------- k_q: q gate + final combine -----------------
// 64 points/block as TWO pipelined 32-pt tiles; static loads (h, zq) prefetched.
__global__ __launch_bounds__(256, 4) void k_q(
    const float* __restrict__ xyz, const float* __restrict__ h,
    const int* __restrict__ knn,
    const float* __restrict__ bq_out,
    const u16* __restrict__ Aqrh,
    const u16* __restrict__ rhT, const u32* __restrict__ zq_ws,
    float* __restrict__ out)
{
  __shared__ __align__(16) u16 bext[32*LDB2];      // 16896 B
  __shared__ __align__(16) float4 relk[2][128];
  __shared__ __align__(16) int4 jlds[2][32];

  int tid = threadIdx.x; int lane = tid & 63; int wv = tid >> 6;
  int l15 = lane & 15, quad = lane >> 4;
  int b = blockIdx.x >> 10, nb = (blockIdx.x & 1023) << 6;
  size_t bN = (size_t)b * NPTS;

  // P0: knn + xyz for both tiles; tile-0 static prefetch (h, zq).
  {
    int t_ = tid >> 7, p_ = (tid >> 2) & 31, k_ = tid & 3;
    int n_ = nb + t_*32 + p_;
    int j = knn[((bN + n_) << 2) + k_];
    ((int*)jlds)[tid] = j;
    const float* xb = xyz + (size_t)b*3*NPTS;
    float cx = xb[n_], cy = xb[NPTS + n_], cz = xb[2*NPTS + n_];
    relk[t_][p_*4 + k_] = make_float4(xb[j]-cx, xb[NPTS+j]-cy, xb[2*NPTS+j]-cz, 0.f);
  }
  float hs0[8]; u32 zq0[8];
  #pragma unroll
  for (int nt = 0; nt < 2; ++nt)
    #pragma unroll
    for (int reg = 0; reg < 4; ++reg){
      size_t idx = (((size_t)(b*HIDC + wv*16 + quad*4 + reg))<<16) + nb + nt*16 + l15;
      hs0[nt*4+reg] = h[idx];
      zq0[nt*4+reg] = zq_ws[idx];
    }
  bar_lgkm();

  const u16* rhTb = rhT + (bN << 6);
  int pA = tid >> 3, chk = tid & 7;
  const u16* cbq = rhTb + chk*8;

#define GATH_Q(G, JL) { \
  int4 jA_ = (JL)[pA]; \
  G[0] = *(const uint4*)(cbq + (((size_t)jA_.x)<<6)); \
  G[1] = *(const uint4*)(cbq + (((size_t)jA_.y)<<6)); \
  G[2] = *(const uint4*)(cbq + (((size_t)jA_.z)<<6)); \
  G[3] = *(const uint4*)(cbq + (((size_t)jA_.w)<<6)); }

#define MOMPACK_Q(G, RK) { \
  float4 r0 = (RK)[pA*4+0], r1 = (RK)[pA*4+1], r2 = (RK)[pA*4+2], r3 = (RK)[pA*4+3]; \
  f32x2 m0[4] = {{0,0},{0,0},{0,0},{0,0}}, mx[4] = {{0,0},{0,0},{0,0},{0,0}}; \
  f32x2 my[4] = {{0,0},{0,0},{0,0},{0,0}}, mz[4] = {{0,0},{0,0},{0,0},{0,0}}; \
  ACCUM(G[0], r0); ACCUM(G[1], r1); ACCUM(G[2], r2); ACCUM(G[3], r3); \
  PACKROW(bext + pA*LDB2, chk*8, 64); }

  int orow = wv*16 + l15;
  const u16* Abase = Aqrh + ((size_t)(quad*64 + orow))*8;
  f32x4 acc[2];
  bf16x8 a0[4], a1[4];

#define LOADAQ(AQ, SS) { \
  _Pragma("unroll") \
  for (int j = 0; j < 4; ++j) AQ[j] = *(const bf16x8*)(Abase + ((SS)*4 + j)*2048); }

#define MFMAGQ(AQ, SS) { \
  _Pragma("unroll") \
  for (int j = 0; j < 4; ++j){ \
    int s_ = (SS)*4 + j; \
    _Pragma("unroll") \
    for (int nt = 0; nt < 2; ++nt){ \
      bf16x8 bb = *(const bf16x8*)(bext + (nt*16 + l15)*LDB2 + s_*32 + quad*8); \
      acc[nt] = MFMA_BF16(AQ[j], bb, acc[nt]); \
    } } }

#define EPI_Q(HS, ZQ, N0) { \
  _Pragma("unroll") \
  for (int nt = 0; nt < 2; ++nt){ \
    _Pragma("unroll") \
    for (int reg = 0; reg < 4; ++reg){ \
      int o = wv*16 + quad*4 + reg; \
      int p = nt*16 + l15; \
      size_t idx = (((size_t)(b*HIDC + o))<<16) + (N0) + p; \
      u32 zqv = ZQ[nt*4+reg]; \
      float qpre = acc[nt][reg] + bq_out[o] + bf2f((u16)(zqv >> 16)); \
      float qf = tanhf_(qpre); \
      float zf = bf2f((u16)(zqv & 0xffffu)); \
      out[idx] = (1.f - zf)*HS[nt*4+reg] + zf*qf; \
    } } }

  uint4 g0[4], g1[4];
  // ---- tile 0 ----
  GATH_Q(g0, jlds[0]);
  __builtin_amdgcn_sched_barrier(0);
  MOMPACK_Q(g0, relk[0]);
  bar_lgkm();

  acc[0] = (f32x4){0,0,0,0}; acc[1] = (f32x4){0,0,0,0};
  LOADAQ(a0, 0);
  LOADAQ(a1, 1);
  MFMAGQ(a0, 0);
  GATH_Q(g1, jlds[1]);          // tile-1 gathers ride under MFMA+epilogue
  __builtin_amdgcn_sched_barrier(0);
  MFMAGQ(a1, 1);
  bar_lgkm();                   // bext MFMA reads done

  EPI_Q(hs0, zq0, nb);
  float hs1[8]; u32 zq1[8];
  #pragma unroll
  for (int nt = 0; nt < 2; ++nt)
    #pragma unroll
    for (int reg = 0; reg < 4; ++reg){
      size_t idx = (((size_t)(b*HIDC + wv*16 + quad*4 + reg))<<16) + nb + 32 + nt*16 + l15;
      hs1[nt*4+reg] = h[idx];
      zq1[nt*4+reg] = zq_ws[idx];
    }

  // ---- tile 1 ----
  MOMPACK_Q(g1, relk[1]);       // g1 had full MFMA(0)+epilogue(0) to land
  bar_lgkm();
  acc[0] = (f32x4){0,0,0,0}; acc[1] = (f32x4){0,0,0,0};
  LOADAQ(a0, 0);
  LOADAQ(a1, 1);
  MFMAGQ(a0, 0);
  MFMAGQ(a1, 1);
  EPI_Q(hs1, zq1, nb + 32);
}

extern "C" void kernel_launch(void* const* d_in, const int* in_sizes, int n_in,
                              void* d_out, int out_size, void* d_ws, size_t ws_size,
                              hipStream_t stream){
  const float* xyz    = (const float*)d_in[0];
  const float* h      = (const float*)d_in[1];
  const float* x      = (const float*)d_in[2];
  const int*   knn    = (const int*)d_in[3];
  const float* wz_pos = (const float*)d_in[4];
  const float* bz_pos = (const float*)d_in[5];
  const float* wz_out = (const float*)d_in[6];
  const float* bz_out = (const float*)d_in[7];
  const float* wr_pos = (const float*)d_in[8];
  const float* br_pos = (const float*)d_in[9];
  const float* wr_out = (const float*)d_in[10];
  const float* br_out = (const float*)d_in[11];
  const float* wq_pos = (const float*)d_in[12];
  const float* bq_pos = (const float*)d_in[13];
  const float* wq_out = (const float*)d_in[14];
  const float* bq_out = (const float*)d_in[15];
  float* out = (float*)d_out;

  // ws (u16): hxT[16777216] | rhT[8388608] | zq[16777216 (u32 x 8388608)] | A[114688]
  u16* ws    = (u16*)d_ws;
  u16* hxT   = ws;
  u16* rhT   = ws + 16777216;
  u32* zq_ws = (u32*)(ws + 25165824);
  u16* A     = ws + 41943040;

  kprep<<<448, 256, 0, stream>>>(wz_out, wz_pos, bz_pos, wr_out, wr_pos, br_pos,
                                 wq_out, wq_pos, bq_pos, A);
  k_pack<<<2048, 256, 0, stream>>>(h, x, hxT);
  k_zr<<<2048, 256, 0, stream>>>(xyz, h, knn, bz_out, br_out, A, hxT, rhT, zq_ws);
  k_q<<<2048, 256, 0, stream>>>(xyz, h, knn, bq_out, A + 98304, rhT, zq_ws, out);
}

// Round 5
// 222.157 us; speedup vs baseline: 1.2640x; 1.2640x over previous
//
#include <hip/hip_runtime.h>

#define NPTS 65536
#define BATCH 2
#define CCH 128
#define HIDC 64
#define LDB 520      // k_zr bext row stride u16 (512+8 pad)
#define LDB2 264     // k_q bext row stride u16 (256+8 pad)
#define PLD 130      // k_pack tile row stride u16

typedef unsigned short u16;
typedef unsigned int u32;
typedef __bf16 bf16_t;
typedef bf16_t bf16x8 __attribute__((ext_vector_type(8)));
typedef float f32x4 __attribute__((ext_vector_type(4)));
typedef float f32x2 __attribute__((ext_vector_type(2)));

__device__ __forceinline__ u16 f2bf(float f){
  union { float f; unsigned u; } v; v.f = f;
  unsigned r = v.u + 0x7FFFu + ((v.u >> 16) & 1u);
  return (u16)(r >> 16);
}
__device__ __forceinline__ float bf2f(u16 u){
  union { unsigned u; float f; } v; v.u = ((unsigned)u) << 16; return v.f;
}
__device__ __forceinline__ u32 pkrn(float a, float b){
  union { float f; u32 u; } ua, ub; ua.f = a; ub.f = b;
  return ((ua.u + 0x8000u) >> 16) | ((ub.u + 0x8000u) & 0xffff0000u);
}
__device__ __forceinline__ float sigmoidf_(float v){ return 1.f/(1.f+__expf(-v)); }
__device__ __forceinline__ float tanhf_(float v){
  v = fminf(10.f, fmaxf(-10.f, v));
  float e = __expf(2.f*v);
  return (e-1.f)/(e+1.f);
}

// Fused: blocks <2048 transpose h,x [B,64,N] fp32 -> hxT [B,N,128] bf16 rows;
// blocks >=2048 build the fragment-permuted A matrices (bf16).
// A layout: first 98304: Az|Ar|Aq at K=512; then 16384: Aqrh at K=256.
__global__ __launch_bounds__(256) void k_prep_pack(
    const float* __restrict__ h, const float* __restrict__ x, u16* __restrict__ hxT,
    const float* __restrict__ wz, const float* __restrict__ wzp, const float* __restrict__ bzp,
    const float* __restrict__ wr, const float* __restrict__ wrp, const float* __restrict__ brp,
    const float* __restrict__ wq, const float* __restrict__ wqp, const float* __restrict__ bqp,
    u16* __restrict__ A){
  __shared__ __align__(16) u16 tile[64*PLD];
  int tid = threadIdx.x;
  if (blockIdx.x < 2048){
    int b = blockIdx.x >> 10, n0 = (blockIdx.x & 1023) << 6;
    #pragma unroll
    for (int i = 0; i < 8; ++i){
      int cc = (tid>>4) + i*16;                      // 0..127
      int nn = (tid & 15)*4;
      const float* src = (cc < HIDC)
          ? (h + (((size_t)(b*HIDC + cc))<<16) + n0 + nn)
          : (x + (((size_t)(b*HIDC + cc - HIDC))<<16) + n0 + nn);
      float4 v = *(const float4*)src;
      tile[(nn+0)*PLD + cc] = f2bf(v.x);
      tile[(nn+1)*PLD + cc] = f2bf(v.y);
      tile[(nn+2)*PLD + cc] = f2bf(v.z);
      tile[(nn+3)*PLD + cc] = f2bf(v.w);
    }
    __syncthreads();
    #pragma unroll
    for (int i = 0; i < 4; ++i){
      int tsk = tid + (i<<8);                        // 0..1023: 64 n x 16 chunks
      int n = tsk>>4, ch = (tsk&15)*8;
      uint4 v = *(const uint4*)(tile + n*PLD + ch);
      *(uint4*)(hxT + (((size_t)(b<<16) + n0 + n)<<7) + ch) = v;
    }
  } else {
    int idx = (blockIdx.x - 2048)*256 + tid;         // 0..114687
    if (idx < 98304){
      int t = idx & 7, o = (idx>>3)&63, quad = (idx>>9)&3, s = (idx>>11)&15, g = idx>>15;
      int pk = s*32 + quad*8 + t;
      int j = pk>>7, chunk = (pk>>3)&15, tt = pk&7;
      int orig = chunk*32 + j*8 + tt;
      int c = orig>>2, m = orig&3;
      const float* W  = (g==0)? wz  : (g==1)? wr  : wq;
      const float* wp = (g==0)? wzp : (g==1)? wrp : wqp;
      const float* bp = (g==0)? bzp : (g==1)? brp : bqp;
      float coef = m ? wp[c*3 + m - 1] : bp[c];
      A[idx] = f2bf(W[o*CCH + c] * coef);
    } else {
      int i2 = idx - 98304;
      int t = i2 & 7, o = (i2>>3)&63, quad = (i2>>9)&3, s = (i2>>11)&7;
      int k2 = s*32 + quad*8 + t;
      int j = k2>>6, chunk = (k2>>3)&7, tt = k2&7;
      int orig = chunk*32 + j*8 + tt;
      int c = orig>>2, m = orig&3;                   // c in [0,64): rh channels
      float coef = m ? wqp[c*3 + m - 1] : bqp[c];
      A[idx] = f2bf(wq[o*CCH + c] * coef);
    }
  }
}

// Moment accumulation on f32x2 (v_pk_fma_f32).
#define ACCUM(gv, rv) { \
  u32 dw_[4] = {gv.x, gv.y, gv.z, gv.w}; \
  _Pragma("unroll") \
  for (int q_ = 0; q_ < 4; ++q_){ \
    union { u32 u; float f; } lo_, hi_; \
    lo_.u = dw_[q_] << 16; hi_.u = dw_[q_] & 0xffff0000u; \
    f32x2 v_ = {lo_.f, hi_.f}; \
    m0[q_] += v_; mx[q_] += rv.x * v_; my[q_] += rv.y * v_; mz[q_] += rv.z * v_; \
  } }

#define PACKROW(row, CHOFF, STRIDE) { \
  _Pragma("unroll") \
  for (int j_ = 0; j_ < 4; ++j_){ \
    uint4 v_; \
    v_.x = pkrn(m0[j_].x, mx[j_].x); v_.y = pkrn(my[j_].x, mz[j_].x); \
    v_.z = pkrn(m0[j_].y, mx[j_].y); v_.w = pkrn(my[j_].y, mz[j_].y); \
    *(uint4*)((row) + j_*(STRIDE) + (CHOFF)) = v_; \
  } }

#define MFMA_BF16(A_, B_, C_) __builtin_amdgcn_mfma_f32_16x16x32_bf16(A_, B_, C_, 0, 0, 0)

// z & r gates + q-gate x-partial. 32 points/block, 4 blocks/CU (r0 geometry).
// h for rh-product read as bf16 from hxT (static addr, issued at kernel start);
// z & qx packed into one u32 stream.
__global__ __launch_bounds__(256, 4) void k_zr(
    const float* __restrict__ xyz,
    const int* __restrict__ knn,
    const float* __restrict__ bz_out, const float* __restrict__ br_out,
    const u16* __restrict__ Azr,    // Az at 0, Ar at +32768, Aq at +65536
    const u16* __restrict__ hxT, u16* __restrict__ rhT,
    u32* __restrict__ zq_ws)
{
  __shared__ __align__(16) u16 bext[32*LDB];       // 33280 B
  __shared__ __align__(16) float4 relk[128];
  __shared__ __align__(16) int4 jlds[32];

  int tid = threadIdx.x; int lane = tid & 63; int wv = tid >> 6;
  int l15 = lane & 15, quad = lane >> 4;
  int b = blockIdx.x >> 11, n0 = (blockIdx.x & 2047) << 5;
  size_t bN = (size_t)b * NPTS;

  // Static h prefetch (bf16 from hxT): issued first, latency hides under knn chain.
  uint2 hraw[2];
  #pragma unroll
  for (int nt = 0; nt < 2; ++nt)
    hraw[nt] = *(const uint2*)(hxT + ((bN + n0 + nt*16 + l15)<<7) + wv*16 + quad*4);

  if (tid < 128){
    int p = tid >> 2, k = tid & 3;
    int j = knn[((bN + n0 + p) << 2) + k];
    ((int*)jlds)[tid] = j;
    const float* xb = xyz + (size_t)b*3*NPTS;
    float cx = xb[n0+p], cy = xb[NPTS + n0+p], cz = xb[2*NPTS + n0+p];
    relk[tid] = make_float4(xb[j]-cx, xb[NPTS+j]-cy, xb[2*NPTS+j]-cz, 0.f);
  }
  __syncthreads();

  // gather: 2 tasks/thread, all 8 loads issued before any accumulation
  const u16* hxTb = hxT + (bN << 7);
  int pA = tid >> 4, chk = tid & 15;
  int pB = pA + 16;
  int4 jA = jlds[pA], jB = jlds[pB];
  const u16* cb = hxTb + chk*8;
  uint4 ga0 = *(const uint4*)(cb + (((size_t)jA.x)<<7));
  uint4 ga1 = *(const uint4*)(cb + (((size_t)jA.y)<<7));
  uint4 ga2 = *(const uint4*)(cb + (((size_t)jA.z)<<7));
  uint4 ga3 = *(const uint4*)(cb + (((size_t)jA.w)<<7));
  uint4 gb0 = *(const uint4*)(cb + (((size_t)jB.x)<<7));
  uint4 gb1 = *(const uint4*)(cb + (((size_t)jB.y)<<7));
  uint4 gb2 = *(const uint4*)(cb + (((size_t)jB.z)<<7));
  uint4 gb3 = *(const uint4*)(cb + (((size_t)jB.w)<<7));
  {
    float4 r0 = relk[pA*4+0], r1 = relk[pA*4+1], r2 = relk[pA*4+2], r3 = relk[pA*4+3];
    f32x2 m0[4] = {{0,0},{0,0},{0,0},{0,0}}, mx[4] = {{0,0},{0,0},{0,0},{0,0}};
    f32x2 my[4] = {{0,0},{0,0},{0,0},{0,0}}, mz[4] = {{0,0},{0,0},{0,0},{0,0}};
    ACCUM(ga0, r0); ACCUM(ga1, r1); ACCUM(ga2, r2); ACCUM(ga3, r3);
    PACKROW(bext + pA*LDB, chk*8, 128);
  }
  {
    float4 r0 = relk[pB*4+0], r1 = relk[pB*4+1], r2 = relk[pB*4+2], r3 = relk[pB*4+3];
    f32x2 m0[4] = {{0,0},{0,0},{0,0},{0,0}}, mx[4] = {{0,0},{0,0},{0,0},{0,0}};
    f32x2 my[4] = {{0,0},{0,0},{0,0},{0,0}}, mz[4] = {{0,0},{0,0},{0,0},{0,0}};
    ACCUM(gb0, r0); ACCUM(gb1, r1); ACCUM(gb2, r2); ACCUM(gb3, r3);
    PACKROW(bext + pB*LDB, chk*8, 128);
  }
  __syncthreads();

  // MFMA: z,r over K=512; q x-part over the s&2 slices (c>=64).
  // s-slices in 4 groups of 4, A-fragments double-buffered one group ahead.
  int orow = wv*16 + l15;
  const u16* Abase = Azr + ((size_t)(quad*64 + orow))*8;   // + s*2048 walks s-slices

  f32x4 accz[2], accr[2], accq[2];
  #pragma unroll
  for (int nt = 0; nt < 2; ++nt){
    accz[nt] = (f32x4){0,0,0,0}; accr[nt] = (f32x4){0,0,0,0}; accq[nt] = (f32x4){0,0,0,0};
  }

  bf16x8 az0[4], ar0[4], aq0[2], az1[4], ar1[4], aq1[2];
#define LOADA(AZ, AR, AQ, SS) { \
  _Pragma("unroll") \
  for (int j = 0; j < 4; ++j){ \
    AZ[j] = *(const bf16x8*)(Abase + ((SS)*4 + j)*2048); \
    AR[j] = *(const bf16x8*)(Abase + 32768 + ((SS)*4 + j)*2048); \
  } \
  AQ[0] = *(const bf16x8*)(Abase + 65536 + ((SS)*4 + 2)*2048); \
  AQ[1] = *(const bf16x8*)(Abase + 65536 + ((SS)*4 + 3)*2048); }

#define MFMAG(AZ, AR, AQ, SS) { \
  _Pragma("unroll") \
  for (int j = 0; j < 4; ++j){ \
    int s_ = (SS)*4 + j; \
    _Pragma("unroll") \
    for (int nt = 0; nt < 2; ++nt){ \
      bf16x8 bb = *(const bf16x8*)(bext + (nt*16 + l15)*LDB + s_*32 + quad*8); \
      accz[nt] = MFMA_BF16(AZ[j], bb, accz[nt]); \
      accr[nt] = MFMA_BF16(AR[j], bb, accr[nt]); \
      if (j >= 2) accq[nt] = MFMA_BF16(AQ[j-2], bb, accq[nt]); \
    } } }

  LOADA(az0, ar0, aq0, 0);
  LOADA(az1, ar1, aq1, 1);
  MFMAG(az0, ar0, aq0, 0);
  LOADA(az0, ar0, aq0, 2);
  MFMAG(az1, ar1, aq1, 1);
  LOADA(az1, ar1, aq1, 3);
  MFMAG(az0, ar0, aq0, 2);
  MFMAG(az1, ar1, aq1, 3);

  __syncthreads();   // bext reads done; reuse as staging

  u32* zqst = (u32*)bext;            // [64 o][44] u32 = 11264 B (44: bank-spread, 16B rows)
  u16* rhst = bext + 5632;           // [32 p][72] u16 = 4608 B
  #pragma unroll
  for (int nt = 0; nt < 2; ++nt){
    u32 hr = nt ? hraw[1].x : hraw[0].x;   // placeholder; replaced per reg below
    #pragma unroll
    for (int reg = 0; reg < 4; ++reg){
      int o = wv*16 + quad*4 + reg;               // C/D: row = quad*4+reg
      int p = nt*16 + l15;                        // col = lane&15
      u32 hw = (reg < 2) ? hraw[nt].x : hraw[nt].y;
      u16 hu = (reg & 1) ? (u16)(hw >> 16) : (u16)(hw & 0xffffu);
      float hv = bf2f(hu);
      float zf = sigmoidf_(accz[nt][reg] + bz_out[o]);
      float rf = sigmoidf_(accr[nt][reg] + br_out[o]);
      zqst[o*44 + p] = (u32)f2bf(zf) | (((u32)f2bf(accq[nt][reg])) << 16);
      rhst[p*72 + o] = f2bf(rf * hv);
    }
    (void)hr;
  }
  __syncthreads();

  { // rhT: 32 p x 64 ch = 256 uint4, one per thread
    int p = tid >> 3, ch = (tid & 7)*8;
    uint4 v = *(const uint4*)(rhst + p*72 + ch);
    *(uint4*)(rhT + ((bN + n0 + p)<<6) + ch) = v;
  }
  #pragma unroll
  for (int i = 0; i < 2; ++i){ // zq: 64 o x 32 p u32 = 512 uint4
    int task = tid + (i<<8);
    int o = task >> 3, c4 = (task & 7)*4;
    uint4 v = *(const uint4*)(zqst + o*44 + c4);
    *(uint4*)(zq_ws + (((size_t)(b*HIDC + o))<<16) + n0 + c4) = v;
  }
}

// q gate (rh half via gather, x half from zq_ws) + final combine. 64 points/block.
// Static h/zq prefetched at kernel start (latency hides under knn+gather chain).
__global__ __launch_bounds__(256, 4) void k_q(
    const float* __restrict__ xyz, const float* __restrict__ h,
    const int* __restrict__ knn,
    const float* __restrict__ bq_out,
    const u16* __restrict__ Aqrh,
    const u16* __restrict__ rhT, const u32* __restrict__ zq_ws,
    float* __restrict__ out)
{
  __shared__ __align__(16) u16 bext[64*LDB2];      // 33792 B
  __shared__ __align__(16) float4 relk[256];
  __shared__ __align__(16) int4 jlds[64];

  int tid = threadIdx.x; int lane = tid & 63; int wv = tid >> 6;
  int l15 = lane & 15, quad = lane >> 4;
  int b = blockIdx.x >> 10, n0 = (blockIdx.x & 1023) << 6;
  size_t bN = (size_t)b * NPTS;

  // Static prefetch: h (fp32, output precision) + packed zq.
  float hs[16]; u32 zqp[16];
  #pragma unroll
  for (int nt = 0; nt < 4; ++nt)
    #pragma unroll
    for (int reg = 0; reg < 4; ++reg){
      size_t idx = (((size_t)(b*HIDC + wv*16 + quad*4 + reg))<<16) + n0 + nt*16 + l15;
      hs[nt*4+reg] = h[idx];
      zqp[nt*4+reg] = zq_ws[idx];
    }

  {
    int p = tid >> 2, k = tid & 3;
    int j = knn[((bN + n0 + p) << 2) + k];
    ((int*)jlds)[tid] = j;
    const float* xb = xyz + (size_t)b*3*NPTS;
    float cx = xb[n0+p], cy = xb[NPTS + n0+p], cz = xb[2*NPTS + n0+p];
    relk[tid] = make_float4(xb[j]-cx, xb[NPTS+j]-cy, xb[2*NPTS+j]-cz, 0.f);
  }
  __syncthreads();

  // gather rh rows (64 ch = 128 B): 2 tasks/thread, 8 loads in flight
  const u16* rhTb = rhT + (bN << 6);
  int pA = tid >> 3, chk = tid & 7;
  int pB = pA + 32;
  int4 jA = jlds[pA], jB = jlds[pB];
  const u16* cb = rhTb + chk*8;
  uint4 ga0 = *(const uint4*)(cb + (((size_t)jA.x)<<6));
  uint4 ga1 = *(const uint4*)(cb + (((size_t)jA.y)<<6));
  uint4 ga2 = *(const uint4*)(cb + (((size_t)jA.z)<<6));
  uint4 ga3 = *(const uint4*)(cb + (((size_t)jA.w)<<6));
  uint4 gb0 = *(const uint4*)(cb + (((size_t)jB.x)<<6));
  uint4 gb1 = *(const uint4*)(cb + (((size_t)jB.y)<<6));
  uint4 gb2 = *(const uint4*)(cb + (((size_t)jB.z)<<6));
  uint4 gb3 = *(const uint4*)(cb + (((size_t)jB.w)<<6));
  {
    float4 r0 = relk[pA*4+0], r1 = relk[pA*4+1], r2 = relk[pA*4+2], r3 = relk[pA*4+3];
    f32x2 m0[4] = {{0,0},{0,0},{0,0},{0,0}}, mx[4] = {{0,0},{0,0},{0,0},{0,0}};
    f32x2 my[4] = {{0,0},{0,0},{0,0},{0,0}}, mz[4] = {{0,0},{0,0},{0,0},{0,0}};
    ACCUM(ga0, r0); ACCUM(ga1, r1); ACCUM(ga2, r2); ACCUM(ga3, r3);
    PACKROW(bext + pA*LDB2, chk*8, 64);
  }
  {
    float4 r0 = relk[pB*4+0], r1 = relk[pB*4+1], r2 = relk[pB*4+2], r3 = relk[pB*4+3];
    f32x2 m0[4] = {{0,0},{0,0},{0,0},{0,0}}, mx[4] = {{0,0},{0,0},{0,0},{0,0}};
    f32x2 my[4] = {{0,0},{0,0},{0,0},{0,0}}, mz[4] = {{0,0},{0,0},{0,0},{0,0}};
    ACCUM(gb0, r0); ACCUM(gb1, r1); ACCUM(gb2, r2); ACCUM(gb3, r3);
    PACKROW(bext + pB*LDB2, chk*8, 64);
  }
  __syncthreads();

  int orow = wv*16 + l15;
  const u16* Abase = Aqrh + ((size_t)(quad*64 + orow))*8;  // + s*2048 walks s-slices
  f32x4 acc[4];
  #pragma unroll
  for (int nt = 0; nt < 4; ++nt) acc[nt] = (f32x4){0,0,0,0};

  bf16x8 a0[4], a1[4];
#define LOADAQ(AQ, SS) { \
  _Pragma("unroll") \
  for (int j = 0; j < 4; ++j) AQ[j] = *(const bf16x8*)(Abase + ((SS)*4 + j)*2048); }

#define MFMAGQ(AQ, SS) { \
  _Pragma("unroll") \
  for (int j = 0; j < 4; ++j){ \
    int s_ = (SS)*4 + j; \
    _Pragma("unroll") \
    for (int nt = 0; nt < 4; ++nt){ \
      bf16x8 bb = *(const bf16x8*)(bext + (nt*16 + l15)*LDB2 + s_*32 + quad*8); \
      acc[nt] = MFMA_BF16(AQ[j], bb, acc[nt]); \
    } } }

  LOADAQ(a0, 0);
  LOADAQ(a1, 1);
  MFMAGQ(a0, 0);
  MFMAGQ(a1, 1);

  #pragma unroll
  for (int nt = 0; nt < 4; ++nt){
    #pragma unroll
    for (int reg = 0; reg < 4; ++reg){
      int o = wv*16 + quad*4 + reg;
      int p = nt*16 + l15;
      size_t idx = (((size_t)(b*HIDC + o))<<16) + n0 + p;
      u32 zqv = zqp[nt*4+reg];
      float qpre = acc[nt][reg] + bq_out[o] + bf2f((u16)(zqv >> 16));
      float qf = tanhf_(qpre);
      float zf = bf2f((u16)(zqv & 0xffffu));
      out[idx] = (1.f - zf)*hs[nt*4+reg] + zf*qf;
    }
  }
}

extern "C" void kernel_launch(void* const* d_in, const int* in_sizes, int n_in,
                              void* d_out, int out_size, void* d_ws, size_t ws_size,
                              hipStream_t stream){
  const float* xyz    = (const float*)d_in[0];
  const float* h      = (const float*)d_in[1];
  const float* x      = (const float*)d_in[2];
  const int*   knn    = (const int*)d_in[3];
  const float* wz_pos = (const float*)d_in[4];
  const float* bz_pos = (const float*)d_in[5];
  const float* wz_out = (const float*)d_in[6];
  const float* bz_out = (const float*)d_in[7];
  const float* wr_pos = (const float*)d_in[8];
  const float* br_pos = (const float*)d_in[9];
  const float* wr_out = (const float*)d_in[10];
  const float* br_out = (const float*)d_in[11];
  const float* wq_pos = (const float*)d_in[12];
  const float* bq_pos = (const float*)d_in[13];
  const float* wq_out = (const float*)d_in[14];
  const float* bq_out = (const float*)d_in[15];
  float* out = (float*)d_out;

  // ws (u16): hxT[16777216] | rhT[8388608] | zq[u32 x 8388608] | A[114688]
  u16* ws    = (u16*)d_ws;
  u16* hxT   = ws;
  u16* rhT   = ws + 16777216;
  u32* zq_ws = (u32*)(ws + 25165824);
  u16* A     = ws + 41943040;

  k_prep_pack<<<2496, 256, 0, stream>>>(h, x, hxT,
      wz_out, wz_pos, bz_pos, wr_out, wr_pos, br_pos, wq_out, wq_pos, bq_pos, A);
  k_zr<<<4096, 256, 0, stream>>>(xyz, knn, bz_out, br_out, A, hxT, rhT, zq_ws);
  k_q<<<2048, 256, 0, stream>>>(xyz, h, knn, bq_out, A + 98304, rhT, zq_ws, out);
}